// Round 14
// baseline (50.236 us; speedup 1.0000x reference)
//
#include <hip/hip_runtime.h>

#define NN   10000
#define NE   640000
#define DIM  128
#define NTILES (NN / 16)        // 625
#define NBIN  320               // bins of 32 rows; valid bins 0..312
#define CAPB  4096              // per-bin capacity (mean 2048, ~45 sigma headroom)
#define EPB   8192              // edges per fill block (256 thr x 32, two passes)
#define FILL_BLOCKS ((NE + EPB - 1) / EPB)   // 79
#define CONV_THREADS 160000                  // x->bf16: 8 floats/thread
#define CONV_BLOCKS ((CONV_THREADS + 255) / 256)  // 625
#define CLCAP 512               // per-node dense colid list capacity (deg max ~110)
#define ZW_ITEMS (32768 + NBIN) // weight pack + bincnt zero

typedef __attribute__((ext_vector_type(8))) short bf16x8;
typedef __attribute__((ext_vector_type(8))) unsigned short u16x8;
typedef __attribute__((ext_vector_type(4))) float f32x4;

__device__ inline unsigned short f2bf(float f) {
    unsigned u = __builtin_bit_cast(unsigned, f);
    unsigned r = (u + 0x7fffu + ((u >> 16) & 1u)) >> 16;
    return (unsigned short)r;
}
__device__ inline float bf2f(unsigned short u) {
    return __builtin_bit_cast(float, (unsigned)u << 16);
}

// ===========================================================================
// PRIMARY ws layout (bytes), total 7,869,696 (round-13 proven):
//   bincnt int[320]              @ 0          (1,280)      zeroed in zw
//   binmem u32[320][4096]        @ 1,280      (5,242,880)  packed (row&31)<<14|col
//   xb     ushort[1,280,000]     @ 5,244,160  (2,560,000)  bf16 of x
//   W1p    ushort[16384]         @ 7,804,160  (32,768)     bf16 MFMA-frag order
//   W2p    ushort[16384]         @ 7,836,928  (32,768)
// ===========================================================================
#define OFF_BINMEM 1280
#define OFF_XB     5244160
#define OFF_W1P    7804160
#define OFF_W2P    7836928
#define WS_NEED    7869696

// --- zw: pack W1/W2 into MFMA B-frag bf16 order + zero bincnt ---------------
// B-frag for mfma_f32_16x16x32_bf16: lane l elem e = B[kt*32+(l>>4)*8+e][nt*16+(l&15)].
__global__ __launch_bounds__(256) void zw_kernel(
        const float* __restrict__ W1, const float* __restrict__ W2,
        unsigned short* __restrict__ W1p, unsigned short* __restrict__ W2p,
        int* __restrict__ bincnt) {
    int id = blockIdx.x * 256 + threadIdx.x;
    if (id < 32768) {
        const float* W = (id < 16384) ? W1 : W2;
        unsigned short* Wp = (id < 16384) ? W1p : W2p;
        int f = id & 16383;
        int e = f & 7, lane = (f >> 3) & 63, kt = (f >> 9) & 3, nt = f >> 11;
        int kglob = kt * 32 + (lane >> 4) * 8 + e;
        int jglob = nt * 16 + (lane & 15);
        Wp[f] = f2bf(W[kglob * DIM + jglob]);
    } else if (id < ZW_ITEMS) {
        bincnt[id - 32768] = 0;
    }
}

// --- build: binned fill (blocks 0..78, two-pass) + x->bf16 (blocks 79..703) -
// fill: pass1 LDS histogram; one device chunk-claim per (block,bin) (~25K
// total device atomics); pass2 re-reads ei (L2-hot) and places via LDS
// running offsets. convert: independent of bincnt -> overlaps fill latency.
__global__ __launch_bounds__(256) void build_kernel(
        const int* __restrict__ ei, const float* __restrict__ x,
        int* __restrict__ bincnt, unsigned* __restrict__ binmem,
        unsigned short* __restrict__ xb) {
    const int t = threadIdx.x;
    if (blockIdx.x < FILL_BLOCKS) {
        __shared__ int hist[NBIN];
        for (int b = t; b < NBIN; b += 256) hist[b] = 0;
        __syncthreads();
        const int e0 = blockIdx.x * EPB;
        // pass 1: count
        for (int i = 0; i < EPB / 256; ++i) {
            int idx = e0 + i * 256 + t;
            if (idx < NE)
                atomicAdd(&hist[ei[2 * idx] >> 5], 1);
        }
        __syncthreads();
        // claim per-bin chunks; hist becomes running write offset
        for (int b = t; b < NBIN; b += 256) {
            int h = hist[b];
            hist[b] = (h > 0) ? atomicAdd(&bincnt[b], h) : 0;
        }
        __syncthreads();
        // pass 2: place (ei re-read is L2-hot, 64 KB/block)
        for (int i = 0; i < EPB / 256; ++i) {
            int idx = e0 + i * 256 + t;
            if (idx < NE) {
                int2 rc = *reinterpret_cast<const int2*>(ei + 2 * idx);
                int bn = rc.x >> 5;
                int pos = atomicAdd(&hist[bn], 1);
                if (pos < CAPB)
                    binmem[(size_t)bn * CAPB + pos] =
                        ((unsigned)(rc.x & 31) << 14) | (unsigned)rc.y;
            }
        }
    } else {
        int pid = (blockIdx.x - FILL_BLOCKS) * 256 + t;
        if (pid < CONV_THREADS) {
            int i = pid * 8;
            float4 a = *reinterpret_cast<const float4*>(x + i);
            float4 b = *reinterpret_cast<const float4*>(x + i + 4);
            u16x8 pk;
            pk[0] = f2bf(a.x); pk[1] = f2bf(a.y); pk[2] = f2bf(a.z); pk[3] = f2bf(a.w);
            pk[4] = f2bf(b.x); pk[5] = f2bf(b.y); pk[6] = f2bf(b.z); pk[7] = f2bf(b.w);
            *reinterpret_cast<u16x8*>(xb + i) = pk;
        }
    }
}

// --- fused gather + MLP (round-13 proven) -----------------------------------
__global__ __launch_bounds__(256) void gather_mlp_kernel(
        const unsigned short* __restrict__ xb,
        const int* __restrict__ bincnt,
        const unsigned* __restrict__ binmem,
        const unsigned short* __restrict__ W1p,
        const unsigned short* __restrict__ W2p,
        const float* __restrict__ b1,
        const float* __restrict__ b2,
        float* __restrict__ out) {
    __shared__ __align__(16) unsigned short aggs[16][136];
    __shared__ __align__(16) unsigned short hbuf[16][136];
    __shared__ __align__(16) unsigned short clist[16][CLCAP];
    __shared__ int lcnt[16];

    const int row0 = blockIdx.x * 16;
    const int t = threadIdx.x;

    // ---- prologue: bin segment -> per-node dense colid lists ----
    if (t < 16) lcnt[t] = 0;
    __syncthreads();
    {
        const int bin  = blockIdx.x >> 1;
        const int half = blockIdx.x & 1;
        int bc = bincnt[bin];
        bc = (bc > CAPB) ? CAPB : bc;
        const unsigned* bm = binmem + (size_t)bin * CAPB;
        for (int k = t; k < bc; k += 256) {
            unsigned p = bm[k];
            int rl = p >> 14;                  // 0..31 within bin
            if ((rl >> 4) == half) {
                int n = rl & 15;
                int slot = atomicAdd(&lcnt[n], 1);
                if (slot < CLCAP)
                    clist[n][slot] = (unsigned short)(p & 0x3FFFu);
            }
        }
    }
    __syncthreads();

    // ---- dense gather: 16 lanes/node, 4-deep ILP ----
    {
        const int n = t >> 4, l = t & 15;
        int deg = lcnt[n];
        deg = (deg > CLCAP) ? CLCAP : deg;
        const size_t lo = l * 8;

        float a0[8], a1[8], a2[8], a3[8];
        {
            u16x8 v = *reinterpret_cast<const u16x8*>(xb + (size_t)(row0 + n) * DIM + lo);
            #pragma unroll
            for (int j = 0; j < 8; ++j) { a0[j] = bf2f(v[j]); a1[j] = 0.f; a2[j] = 0.f; a3[j] = 0.f; }
        }
        int k = 0;
        for (; k + 4 <= deg; k += 4) {
            int c0 = clist[n][k + 0];
            int c1 = clist[n][k + 1];
            int c2 = clist[n][k + 2];
            int c3 = clist[n][k + 3];
            u16x8 v0 = *reinterpret_cast<const u16x8*>(xb + (size_t)c0 * DIM + lo);
            u16x8 v1 = *reinterpret_cast<const u16x8*>(xb + (size_t)c1 * DIM + lo);
            u16x8 v2 = *reinterpret_cast<const u16x8*>(xb + (size_t)c2 * DIM + lo);
            u16x8 v3 = *reinterpret_cast<const u16x8*>(xb + (size_t)c3 * DIM + lo);
            #pragma unroll
            for (int j = 0; j < 8; ++j) {
                a0[j] += bf2f(v0[j]);
                a1[j] += bf2f(v1[j]);
                a2[j] += bf2f(v2[j]);
                a3[j] += bf2f(v3[j]);
            }
        }
        for (; k < deg; ++k) {
            int c = clist[n][k];
            u16x8 v = *reinterpret_cast<const u16x8*>(xb + (size_t)c * DIM + lo);
            #pragma unroll
            for (int j = 0; j < 8; ++j) a0[j] += bf2f(v[j]);
        }
        u16x8 pk;
        #pragma unroll
        for (int j = 0; j < 8; ++j) pk[j] = f2bf((a0[j] + a1[j]) + (a2[j] + a3[j]));
        *reinterpret_cast<u16x8*>(&aggs[n][l * 8]) = pk;
    }
    __syncthreads();

    // ---- MLP: wave w owns cols [32w, 32w+32) of both layers ----
    const int wid  = t >> 6;
    const int lane = t & 63;
    const int r16  = lane & 15;
    const int kg   = lane >> 4;
    const int drow = kg * 4;

    bf16x8 af[4];
    #pragma unroll
    for (int kt = 0; kt < 4; ++kt)
        af[kt] = *reinterpret_cast<const bf16x8*>(&aggs[r16][kt * 32 + kg * 8]);

    const f32x4 zero = {0.f, 0.f, 0.f, 0.f};
    f32x4 acc1[2] = {zero, zero};
    #pragma unroll
    for (int kt = 0; kt < 4; ++kt) {
        #pragma unroll
        for (int q = 0; q < 2; ++q) {
            int nt = wid * 2 + q;
            bf16x8 w = *reinterpret_cast<const bf16x8*>(
                W1p + ((nt * 4 + kt) * 64 + lane) * 8);
            acc1[q] = __builtin_amdgcn_mfma_f32_16x16x32_bf16(af[kt], w, acc1[q], 0, 0, 0);
        }
    }
    #pragma unroll
    for (int q = 0; q < 2; ++q) {
        int nt = wid * 2 + q;
        float bv = b1[nt * 16 + r16];
        #pragma unroll
        for (int r = 0; r < 4; ++r) {
            float h = fmaxf(acc1[q][r] + bv, 0.0f);
            hbuf[drow + r][nt * 16 + r16] = f2bf(h);
        }
    }
    __syncthreads();

    bf16x8 hf[4];
    #pragma unroll
    for (int kt = 0; kt < 4; ++kt)
        hf[kt] = *reinterpret_cast<const bf16x8*>(&hbuf[r16][kt * 32 + kg * 8]);

    f32x4 acc2[2] = {zero, zero};
    #pragma unroll
    for (int kt = 0; kt < 4; ++kt) {
        #pragma unroll
        for (int q = 0; q < 2; ++q) {
            int nt = wid * 2 + q;
            bf16x8 w = *reinterpret_cast<const bf16x8*>(
                W2p + ((nt * 4 + kt) * 64 + lane) * 8);
            acc2[q] = __builtin_amdgcn_mfma_f32_16x16x32_bf16(hf[kt], w, acc2[q], 0, 0, 0);
        }
    }
    #pragma unroll
    for (int q = 0; q < 2; ++q) {
        int nt = wid * 2 + q;
        float bv = b2[nt * 16 + r16];
        #pragma unroll
        for (int r = 0; r < 4; ++r)
            out[(size_t)(row0 + drow + r) * DIM + nt * 16 + r16] = acc2[q][r] + bv;
    }
}

// ===========================================================================
// FALLBACK PATH (round-2 proven f32 kernels; ws >= 2,682,880 B)
// ===========================================================================
__global__ void fb_zero_kernel(int* __restrict__ p, int n) {
    int i = blockIdx.x * blockDim.x + threadIdx.x;
    if (i < n) p[i] = 0;
}
__global__ void fb_count_kernel(const int* __restrict__ ei, int* __restrict__ deg) {
    int e = blockIdx.x * blockDim.x + threadIdx.x;
    if (e < NE) atomicAdd(&deg[ei[2 * e]], 1);
}
__global__ __launch_bounds__(1024) void fb_scan_kernel(const int* __restrict__ deg,
                                                       int* __restrict__ rowptr) {
    __shared__ int wtot[16];
    const int t = threadIdx.x;
    const int base = t * 10;
    int local[10];
    int s = 0;
    #pragma unroll
    for (int i = 0; i < 10; ++i) {
        int v = (base + i < NN) ? deg[base + i] : 0;
        local[i] = s;
        s += v;
    }
    const int mySum = s;
    #pragma unroll
    for (int off = 1; off < 64; off <<= 1) {
        int v = __shfl_up(s, (unsigned)off, 64);
        if ((t & 63) >= off) s += v;
    }
    if ((t & 63) == 63) wtot[t >> 6] = s;
    __syncthreads();
    if (t == 0) {
        int run = 0;
        #pragma unroll
        for (int i = 0; i < 16; ++i) { int v = wtot[i]; wtot[i] = run; run += v; }
    }
    __syncthreads();
    const int ex = wtot[t >> 6] + (s - mySum);
    #pragma unroll
    for (int i = 0; i < 10; ++i)
        if (base + i < NN) rowptr[base + i] = ex + local[i];
    if (t == 1023) rowptr[NN] = ex + mySum;
}
__global__ void fb_fill_kernel(const int* __restrict__ ei, const int* __restrict__ rowptr,
                               int* __restrict__ fill, int* __restrict__ colidx) {
    int e = blockIdx.x * blockDim.x + threadIdx.x;
    if (e < NE) {
        int r = ei[2 * e], c = ei[2 * e + 1];
        colidx[rowptr[r] + atomicAdd(&fill[r], 1)] = c;
    }
}
__global__ __launch_bounds__(128) void fb_gather_kernel(const float* __restrict__ x,
                                                        const int* __restrict__ rowptr,
                                                        const int* __restrict__ colidx,
                                                        float* __restrict__ agg) {
    const int n = blockIdx.x, j = threadIdx.x;
    const int s = rowptr[n], e = rowptr[n + 1];
    float acc = x[(size_t)n * DIM + j];
    float a0 = 0.f, a1 = 0.f, a2 = 0.f, a3 = 0.f;
    int k = s;
    for (; k + 4 <= e; k += 4) {
        a0 += x[(size_t)colidx[k + 0] * DIM + j];
        a1 += x[(size_t)colidx[k + 1] * DIM + j];
        a2 += x[(size_t)colidx[k + 2] * DIM + j];
        a3 += x[(size_t)colidx[k + 3] * DIM + j];
    }
    for (; k < e; ++k) acc += x[(size_t)colidx[k] * DIM + j];
    agg[(size_t)n * DIM + j] = acc + (a0 + a1) + (a2 + a3);
}
__global__ __launch_bounds__(512) void fb_mlp_kernel(
        const float* __restrict__ agg,
        const float* __restrict__ W1, const float* __restrict__ b1,
        const float* __restrict__ W2, const float* __restrict__ b2,
        float* __restrict__ out) {
    __shared__ float w1s[DIM * DIM];
    __shared__ float w2s[DIM * DIM];
    __shared__ float b1s[DIM], b2s[DIM];
    __shared__ float as[4][DIM], hs[4][DIM];
    for (int i = threadIdx.x; i < DIM * DIM; i += blockDim.x) { w1s[i] = W1[i]; w2s[i] = W2[i]; }
    if (threadIdx.x < DIM) { b1s[threadIdx.x] = b1[threadIdx.x]; b2s[threadIdx.x] = b2[threadIdx.x]; }
    __syncthreads();
    const int r = threadIdx.x >> 7, j = threadIdx.x & 127;
    for (int base = blockIdx.x * 4; base < NN; base += gridDim.x * 4) {
        int rowid = base + r;
        as[r][j] = (rowid < NN) ? agg[(size_t)rowid * DIM + j] : 0.0f;
        __syncthreads();
        float acc = b1s[j];
        #pragma unroll 8
        for (int k = 0; k < DIM; ++k) acc = fmaf(as[r][k], w1s[k * DIM + j], acc);
        hs[r][j] = fmaxf(acc, 0.0f);
        __syncthreads();
        float acc2 = b2s[j];
        #pragma unroll 8
        for (int k = 0; k < DIM; ++k) acc2 = fmaf(hs[r][k], w2s[k * DIM + j], acc2);
        if (rowid < NN) out[(size_t)rowid * DIM + j] = acc2;
        __syncthreads();
    }
}

// ===========================================================================
extern "C" void kernel_launch(void* const* d_in, const int* in_sizes, int n_in,
                              void* d_out, int out_size, void* d_ws, size_t ws_size,
                              hipStream_t stream) {
    const float* x  = (const float*)d_in[0];
    const int*   ei = (const int*)d_in[1];
    const float* W1 = (const float*)d_in[2];
    const float* b1 = (const float*)d_in[3];
    const float* W2 = (const float*)d_in[4];
    const float* b2 = (const float*)d_in[5];
    float* out = (float*)d_out;

    if (ws_size >= WS_NEED) {
        char* ws = (char*)d_ws;
        int* bincnt = (int*)ws;
        unsigned* binmem = (unsigned*)(ws + OFF_BINMEM);
        unsigned short* xb  = (unsigned short*)(ws + OFF_XB);
        unsigned short* W1p = (unsigned short*)(ws + OFF_W1P);
        unsigned short* W2p = (unsigned short*)(ws + OFF_W2P);

        zw_kernel<<<(ZW_ITEMS + 255) / 256, 256, 0, stream>>>(
            W1, W2, W1p, W2p, bincnt);
        build_kernel<<<FILL_BLOCKS + CONV_BLOCKS, 256, 0, stream>>>(
            ei, x, bincnt, binmem, xb);
        gather_mlp_kernel<<<NTILES, 256, 0, stream>>>(
            xb, bincnt, binmem, W1p, W2p, b1, b2, out);
    } else {
        int* wsI    = (int*)d_ws;
        int* deg    = wsI;
        int* fillc  = wsI + 10240;
        int* rowptr = wsI + 20480;
        int* colidx = wsI + 30720;
        const size_t csr_bytes = (size_t)(30720 + NE) * sizeof(int);
        const size_t agg_bytes = (size_t)NN * DIM * sizeof(float);
        float* agg = (ws_size >= csr_bytes + agg_bytes)
                         ? (float*)((char*)d_ws + csr_bytes) : out;

        fb_zero_kernel<<<(20480 + 255) / 256, 256, 0, stream>>>(deg, 20480);
        fb_count_kernel<<<(NE + 255) / 256, 256, 0, stream>>>(ei, deg);
        fb_scan_kernel<<<1, 1024, 0, stream>>>(deg, rowptr);
        fb_fill_kernel<<<(NE + 255) / 256, 256, 0, stream>>>(ei, rowptr, fillc, colidx);
        fb_gather_kernel<<<NN, 128, 0, stream>>>(x, rowptr, colidx, agg);
        fb_mlp_kernel<<<256, 512, 0, stream>>>(agg, W1, b1, W2, b2, out);
    }
}

// Round 15
// 44.238 us; speedup vs baseline: 1.1356x; 1.1356x over previous
//
#include <hip/hip_runtime.h>

#define NN   10000
#define NE   640000
#define DIM  128
#define NTILES (NN / 16)        // 625
#define NBIN  320               // bins of 32 rows; valid bins 0..312
#define CAPB  4096              // per-bin capacity (mean 2048, ~45 sigma headroom)
#define EPB   2048              // edges per fill block (256 thr x 8, one pass) — 313 blocks
#define FILL_BLOCKS ((NE + EPB - 1) / EPB)   // 313
#define CONV_THREADS 160000                  // x->bf16: 8 floats/thread
#define CONV_BLOCKS ((CONV_THREADS + 255) / 256)  // 625
#define CLCAP 256               // per-node colid list; deg max ~100 (Poisson(64)+4.5σ)
#define ZW_ITEMS (32768 + NBIN) // weight pack + bincnt zero

typedef __attribute__((ext_vector_type(8))) short bf16x8;
typedef __attribute__((ext_vector_type(8))) unsigned short u16x8;
typedef __attribute__((ext_vector_type(4))) float f32x4;

__device__ inline unsigned short f2bf(float f) {
    unsigned u = __builtin_bit_cast(unsigned, f);
    unsigned r = (u + 0x7fffu + ((u >> 16) & 1u)) >> 16;
    return (unsigned short)r;
}
__device__ inline float bf2f(unsigned short u) {
    return __builtin_bit_cast(float, (unsigned)u << 16);
}

// ===========================================================================
// PRIMARY ws layout (bytes), total 7,869,696 (round-13 proven):
//   bincnt int[320]              @ 0          (1,280)      zeroed in zw
//   binmem u32[320][4096]        @ 1,280      (5,242,880)  packed (row&31)<<14|col
//   xb     ushort[1,280,000]     @ 5,244,160  (2,560,000)  bf16 of x
//   W1p    ushort[16384]         @ 7,804,160  (32,768)     bf16 MFMA-frag order
//   W2p    ushort[16384]         @ 7,836,928  (32,768)
// ===========================================================================
#define OFF_BINMEM 1280
#define OFF_XB     5244160
#define OFF_W1P    7804160
#define OFF_W2P    7836928
#define WS_NEED    7869696

// --- zw: pack W1/W2 into MFMA B-frag bf16 order + zero bincnt ---------------
// B-frag for mfma_f32_16x16x32_bf16: lane l elem e = B[kt*32+(l>>4)*8+e][nt*16+(l&15)].
__global__ __launch_bounds__(256) void zw_kernel(
        const float* __restrict__ W1, const float* __restrict__ W2,
        unsigned short* __restrict__ W1p, unsigned short* __restrict__ W2p,
        int* __restrict__ bincnt) {
    int id = blockIdx.x * 256 + threadIdx.x;
    if (id < 32768) {
        const float* W = (id < 16384) ? W1 : W2;
        unsigned short* Wp = (id < 16384) ? W1p : W2p;
        int f = id & 16383;
        int e = f & 7, lane = (f >> 3) & 63, kt = (f >> 9) & 3, nt = f >> 11;
        int kglob = kt * 32 + (lane >> 4) * 8 + e;
        int jglob = nt * 16 + (lane & 15);
        Wp[f] = f2bf(W[kglob * DIM + jglob]);
    } else if (id < ZW_ITEMS) {
        bincnt[id - 32768] = 0;
    }
}

// --- build: one-pass binned fill (blocks 0..312) + x->bf16 (blocks 313..937)
// fill (round-13 proven): LDS rank per edge + one device chunk-claim per
// (block,bin) (~100K device atomics total). convert: independent of bincnt,
// overlaps fill's atomic latency in the same dispatch.
__global__ __launch_bounds__(256) void build_kernel(
        const int* __restrict__ ei, const float* __restrict__ x,
        int* __restrict__ bincnt, unsigned* __restrict__ binmem,
        unsigned short* __restrict__ xb) {
    const int t = threadIdx.x;
    if (blockIdx.x < FILL_BLOCKS) {
        __shared__ int hist[NBIN];
        __shared__ int base_s[NBIN];
        for (int b = t; b < NBIN; b += 256) hist[b] = 0;
        __syncthreads();

        unsigned pk[8];
        int bn[8], rk[8];
        const int e0 = blockIdx.x * EPB;
        #pragma unroll
        for (int i = 0; i < 8; ++i) {
            int idx = e0 + i * 256 + t;
            bn[i] = -1;
            if (idx < NE) {
                int2 rc = *reinterpret_cast<const int2*>(ei + 2 * idx);
                bn[i] = rc.x >> 5;                                  // bin of 32 rows
                pk[i] = ((unsigned)(rc.x & 31) << 14) | (unsigned)rc.y;
                rk[i] = atomicAdd(&hist[bn[i]], 1);                 // LDS rank
            }
        }
        __syncthreads();
        for (int b = t; b < NBIN; b += 256) {
            int h = hist[b];
            base_s[b] = (h > 0) ? atomicAdd(&bincnt[b], h) : 0;     // device chunk claim
        }
        __syncthreads();
        #pragma unroll
        for (int i = 0; i < 8; ++i) {
            if (bn[i] >= 0) {
                int pos = base_s[bn[i]] + rk[i];
                if (pos < CAPB)
                    binmem[(size_t)bn[i] * CAPB + pos] = pk[i];
            }
        }
    } else {
        int pid = (blockIdx.x - FILL_BLOCKS) * 256 + t;
        if (pid < CONV_THREADS) {
            int i = pid * 8;
            float4 a = *reinterpret_cast<const float4*>(x + i);
            float4 b = *reinterpret_cast<const float4*>(x + i + 4);
            u16x8 pk;
            pk[0] = f2bf(a.x); pk[1] = f2bf(a.y); pk[2] = f2bf(a.z); pk[3] = f2bf(a.w);
            pk[4] = f2bf(b.x); pk[5] = f2bf(b.y); pk[6] = f2bf(b.z); pk[7] = f2bf(b.w);
            *reinterpret_cast<u16x8*>(xb + i) = pk;
        }
    }
}

// --- fused gather + MLP (round-13 proven; CLCAP 512->256 for occupancy) -----
__global__ __launch_bounds__(256) void gather_mlp_kernel(
        const unsigned short* __restrict__ xb,
        const int* __restrict__ bincnt,
        const unsigned* __restrict__ binmem,
        const unsigned short* __restrict__ W1p,
        const unsigned short* __restrict__ W2p,
        const float* __restrict__ b1,
        const float* __restrict__ b2,
        float* __restrict__ out) {
    __shared__ __align__(16) unsigned short aggs[16][136];
    __shared__ __align__(16) unsigned short hbuf[16][136];
    __shared__ __align__(16) unsigned short clist[16][CLCAP];
    __shared__ int lcnt[16];

    const int row0 = blockIdx.x * 16;
    const int t = threadIdx.x;

    // ---- prologue: bin segment -> per-node dense colid lists ----
    if (t < 16) lcnt[t] = 0;
    __syncthreads();
    {
        const int bin  = blockIdx.x >> 1;
        const int half = blockIdx.x & 1;
        int bc = bincnt[bin];
        bc = (bc > CAPB) ? CAPB : bc;
        const unsigned* bm = binmem + (size_t)bin * CAPB;
        for (int k = t; k < bc; k += 256) {
            unsigned p = bm[k];
            int rl = p >> 14;                  // 0..31 within bin
            if ((rl >> 4) == half) {
                int n = rl & 15;
                int slot = atomicAdd(&lcnt[n], 1);
                if (slot < CLCAP)
                    clist[n][slot] = (unsigned short)(p & 0x3FFFu);
            }
        }
    }
    __syncthreads();

    // ---- dense gather: 16 lanes/node, 4-deep ILP ----
    {
        const int n = t >> 4, l = t & 15;
        int deg = lcnt[n];
        deg = (deg > CLCAP) ? CLCAP : deg;
        const size_t lo = l * 8;

        float a0[8], a1[8], a2[8], a3[8];
        {
            u16x8 v = *reinterpret_cast<const u16x8*>(xb + (size_t)(row0 + n) * DIM + lo);
            #pragma unroll
            for (int j = 0; j < 8; ++j) { a0[j] = bf2f(v[j]); a1[j] = 0.f; a2[j] = 0.f; a3[j] = 0.f; }
        }
        int k = 0;
        for (; k + 4 <= deg; k += 4) {
            int c0 = clist[n][k + 0];
            int c1 = clist[n][k + 1];
            int c2 = clist[n][k + 2];
            int c3 = clist[n][k + 3];
            u16x8 v0 = *reinterpret_cast<const u16x8*>(xb + (size_t)c0 * DIM + lo);
            u16x8 v1 = *reinterpret_cast<const u16x8*>(xb + (size_t)c1 * DIM + lo);
            u16x8 v2 = *reinterpret_cast<const u16x8*>(xb + (size_t)c2 * DIM + lo);
            u16x8 v3 = *reinterpret_cast<const u16x8*>(xb + (size_t)c3 * DIM + lo);
            #pragma unroll
            for (int j = 0; j < 8; ++j) {
                a0[j] += bf2f(v0[j]);
                a1[j] += bf2f(v1[j]);
                a2[j] += bf2f(v2[j]);
                a3[j] += bf2f(v3[j]);
            }
        }
        for (; k < deg; ++k) {
            int c = clist[n][k];
            u16x8 v = *reinterpret_cast<const u16x8*>(xb + (size_t)c * DIM + lo);
            #pragma unroll
            for (int j = 0; j < 8; ++j) a0[j] += bf2f(v[j]);
        }
        u16x8 pk;
        #pragma unroll
        for (int j = 0; j < 8; ++j) pk[j] = f2bf((a0[j] + a1[j]) + (a2[j] + a3[j]));
        *reinterpret_cast<u16x8*>(&aggs[n][l * 8]) = pk;
    }
    __syncthreads();

    // ---- MLP: wave w owns cols [32w, 32w+32) of both layers ----
    const int wid  = t >> 6;
    const int lane = t & 63;
    const int r16  = lane & 15;
    const int kg   = lane >> 4;
    const int drow = kg * 4;

    bf16x8 af[4];
    #pragma unroll
    for (int kt = 0; kt < 4; ++kt)
        af[kt] = *reinterpret_cast<const bf16x8*>(&aggs[r16][kt * 32 + kg * 8]);

    const f32x4 zero = {0.f, 0.f, 0.f, 0.f};
    f32x4 acc1[2] = {zero, zero};
    #pragma unroll
    for (int kt = 0; kt < 4; ++kt) {
        #pragma unroll
        for (int q = 0; q < 2; ++q) {
            int nt = wid * 2 + q;
            bf16x8 w = *reinterpret_cast<const bf16x8*>(
                W1p + ((nt * 4 + kt) * 64 + lane) * 8);
            acc1[q] = __builtin_amdgcn_mfma_f32_16x16x32_bf16(af[kt], w, acc1[q], 0, 0, 0);
        }
    }
    #pragma unroll
    for (int q = 0; q < 2; ++q) {
        int nt = wid * 2 + q;
        float bv = b1[nt * 16 + r16];
        #pragma unroll
        for (int r = 0; r < 4; ++r) {
            float h = fmaxf(acc1[q][r] + bv, 0.0f);
            hbuf[drow + r][nt * 16 + r16] = f2bf(h);
        }
    }
    __syncthreads();

    bf16x8 hf[4];
    #pragma unroll
    for (int kt = 0; kt < 4; ++kt)
        hf[kt] = *reinterpret_cast<const bf16x8*>(&hbuf[r16][kt * 32 + kg * 8]);

    f32x4 acc2[2] = {zero, zero};
    #pragma unroll
    for (int kt = 0; kt < 4; ++kt) {
        #pragma unroll
        for (int q = 0; q < 2; ++q) {
            int nt = wid * 2 + q;
            bf16x8 w = *reinterpret_cast<const bf16x8*>(
                W2p + ((nt * 4 + kt) * 64 + lane) * 8);
            acc2[q] = __builtin_amdgcn_mfma_f32_16x16x32_bf16(hf[kt], w, acc2[q], 0, 0, 0);
        }
    }
    #pragma unroll
    for (int q = 0; q < 2; ++q) {
        int nt = wid * 2 + q;
        float bv = b2[nt * 16 + r16];
        #pragma unroll
        for (int r = 0; r < 4; ++r)
            out[(size_t)(row0 + drow + r) * DIM + nt * 16 + r16] = acc2[q][r] + bv;
    }
}

// ===========================================================================
// FALLBACK PATH (round-2 proven f32 kernels; ws >= 2,682,880 B)
// ===========================================================================
__global__ void fb_zero_kernel(int* __restrict__ p, int n) {
    int i = blockIdx.x * blockDim.x + threadIdx.x;
    if (i < n) p[i] = 0;
}
__global__ void fb_count_kernel(const int* __restrict__ ei, int* __restrict__ deg) {
    int e = blockIdx.x * blockDim.x + threadIdx.x;
    if (e < NE) atomicAdd(&deg[ei[2 * e]], 1);
}
__global__ __launch_bounds__(1024) void fb_scan_kernel(const int* __restrict__ deg,
                                                       int* __restrict__ rowptr) {
    __shared__ int wtot[16];
    const int t = threadIdx.x;
    const int base = t * 10;
    int local[10];
    int s = 0;
    #pragma unroll
    for (int i = 0; i < 10; ++i) {
        int v = (base + i < NN) ? deg[base + i] : 0;
        local[i] = s;
        s += v;
    }
    const int mySum = s;
    #pragma unroll
    for (int off = 1; off < 64; off <<= 1) {
        int v = __shfl_up(s, (unsigned)off, 64);
        if ((t & 63) >= off) s += v;
    }
    if ((t & 63) == 63) wtot[t >> 6] = s;
    __syncthreads();
    if (t == 0) {
        int run = 0;
        #pragma unroll
        for (int i = 0; i < 16; ++i) { int v = wtot[i]; wtot[i] = run; run += v; }
    }
    __syncthreads();
    const int ex = wtot[t >> 6] + (s - mySum);
    #pragma unroll
    for (int i = 0; i < 10; ++i)
        if (base + i < NN) rowptr[base + i] = ex + local[i];
    if (t == 1023) rowptr[NN] = ex + mySum;
}
__global__ void fb_fill_kernel(const int* __restrict__ ei, const int* __restrict__ rowptr,
                               int* __restrict__ fill, int* __restrict__ colidx) {
    int e = blockIdx.x * blockDim.x + threadIdx.x;
    if (e < NE) {
        int r = ei[2 * e], c = ei[2 * e + 1];
        colidx[rowptr[r] + atomicAdd(&fill[r], 1)] = c;
    }
}
__global__ __launch_bounds__(128) void fb_gather_kernel(const float* __restrict__ x,
                                                        const int* __restrict__ rowptr,
                                                        const int* __restrict__ colidx,
                                                        float* __restrict__ agg) {
    const int n = blockIdx.x, j = threadIdx.x;
    const int s = rowptr[n], e = rowptr[n + 1];
    float acc = x[(size_t)n * DIM + j];
    float a0 = 0.f, a1 = 0.f, a2 = 0.f, a3 = 0.f;
    int k = s;
    for (; k + 4 <= e; k += 4) {
        a0 += x[(size_t)colidx[k + 0] * DIM + j];
        a1 += x[(size_t)colidx[k + 1] * DIM + j];
        a2 += x[(size_t)colidx[k + 2] * DIM + j];
        a3 += x[(size_t)colidx[k + 3] * DIM + j];
    }
    for (; k < e; ++k) acc += x[(size_t)colidx[k] * DIM + j];
    agg[(size_t)n * DIM + j] = acc + (a0 + a1) + (a2 + a3);
}
__global__ __launch_bounds__(512) void fb_mlp_kernel(
        const float* __restrict__ agg,
        const float* __restrict__ W1, const float* __restrict__ b1,
        const float* __restrict__ W2, const float* __restrict__ b2,
        float* __restrict__ out) {
    __shared__ float w1s[DIM * DIM];
    __shared__ float w2s[DIM * DIM];
    __shared__ float b1s[DIM], b2s[DIM];
    __shared__ float as[4][DIM], hs[4][DIM];
    for (int i = threadIdx.x; i < DIM * DIM; i += blockDim.x) { w1s[i] = W1[i]; w2s[i] = W2[i]; }
    if (threadIdx.x < DIM) { b1s[threadIdx.x] = b1[threadIdx.x]; b2s[threadIdx.x] = b2[threadIdx.x]; }
    __syncthreads();
    const int r = threadIdx.x >> 7, j = threadIdx.x & 127;
    for (int base = blockIdx.x * 4; base < NN; base += gridDim.x * 4) {
        int rowid = base + r;
        as[r][j] = (rowid < NN) ? agg[(size_t)rowid * DIM + j] : 0.0f;
        __syncthreads();
        float acc = b1s[j];
        #pragma unroll 8
        for (int k = 0; k < DIM; ++k) acc = fmaf(as[r][k], w1s[k * DIM + j], acc);
        hs[r][j] = fmaxf(acc, 0.0f);
        __syncthreads();
        float acc2 = b2s[j];
        #pragma unroll 8
        for (int k = 0; k < DIM; ++k) acc2 = fmaf(hs[r][k], w2s[k * DIM + j], acc2);
        if (rowid < NN) out[(size_t)rowid * DIM + j] = acc2;
        __syncthreads();
    }
}

// ===========================================================================
extern "C" void kernel_launch(void* const* d_in, const int* in_sizes, int n_in,
                              void* d_out, int out_size, void* d_ws, size_t ws_size,
                              hipStream_t stream) {
    const float* x  = (const float*)d_in[0];
    const int*   ei = (const int*)d_in[1];
    const float* W1 = (const float*)d_in[2];
    const float* b1 = (const float*)d_in[3];
    const float* W2 = (const float*)d_in[4];
    const float* b2 = (const float*)d_in[5];
    float* out = (float*)d_out;

    if (ws_size >= WS_NEED) {
        char* ws = (char*)d_ws;
        int* bincnt = (int*)ws;
        unsigned* binmem = (unsigned*)(ws + OFF_BINMEM);
        unsigned short* xb  = (unsigned short*)(ws + OFF_XB);
        unsigned short* W1p = (unsigned short*)(ws + OFF_W1P);
        unsigned short* W2p = (unsigned short*)(ws + OFF_W2P);

        zw_kernel<<<(ZW_ITEMS + 255) / 256, 256, 0, stream>>>(
            W1, W2, W1p, W2p, bincnt);
        build_kernel<<<FILL_BLOCKS + CONV_BLOCKS, 256, 0, stream>>>(
            ei, x, bincnt, binmem, xb);
        gather_mlp_kernel<<<NTILES, 256, 0, stream>>>(
            xb, bincnt, binmem, W1p, W2p, b1, b2, out);
    } else {
        int* wsI    = (int*)d_ws;
        int* deg    = wsI;
        int* fillc  = wsI + 10240;
        int* rowptr = wsI + 20480;
        int* colidx = wsI + 30720;
        const size_t csr_bytes = (size_t)(30720 + NE) * sizeof(int);
        const size_t agg_bytes = (size_t)NN * DIM * sizeof(float);
        float* agg = (ws_size >= csr_bytes + agg_bytes)
                         ? (float*)((char*)d_ws + csr_bytes) : out;

        fb_zero_kernel<<<(20480 + 255) / 256, 256, 0, stream>>>(deg, 20480);
        fb_count_kernel<<<(NE + 255) / 256, 256, 0, stream>>>(ei, deg);
        fb_scan_kernel<<<1, 1024, 0, stream>>>(deg, rowptr);
        fb_fill_kernel<<<(NE + 255) / 256, 256, 0, stream>>>(ei, rowptr, fillc, colidx);
        fb_gather_kernel<<<NN, 128, 0, stream>>>(x, rowptr, colidx, agg);
        fb_mlp_kernel<<<256, 512, 0, stream>>>(agg, W1, b1, W2, b2, out);
    }
}

// Round 16
// 38.678 us; speedup vs baseline: 1.2988x; 1.1437x over previous
//
#include <hip/hip_runtime.h>

#define NN   10000
#define NE   640000
#define DIM  128
#define NTILES (NN / 16)        // 625
#define NBIN  320               // bins of 32 rows; valid bins 0..312
#define NCHUNK 313              // fill blocks; chunk c = fill block c
#define CAPC  32                // per-(bin,chunk) capacity; Poisson(6.4), P(>32)~1e-20
#define EPB   2048              // edges per fill block (256 thr x 8)
#define WPACK_BLOCKS 128        // 32768 weight elems / 256
#define CONV_THREADS 160000     // x->bf16: 8 floats/thread
#define CONV_BLOCKS 625
#define BUILD_BLOCKS (NCHUNK + WPACK_BLOCKS + CONV_BLOCKS)   // 1066
#define CLCAP 512               // per-node colid list capacity (round-13 proven)

typedef __attribute__((ext_vector_type(8))) short bf16x8;
typedef __attribute__((ext_vector_type(8))) unsigned short u16x8;
typedef __attribute__((ext_vector_type(4))) float f32x4;

__device__ inline unsigned short f2bf(float f) {
    unsigned u = __builtin_bit_cast(unsigned, f);
    unsigned r = (u + 0x7fffu + ((u >> 16) & 1u)) >> 16;
    return (unsigned short)r;
}
__device__ inline float bf2f(unsigned short u) {
    return __builtin_bit_cast(float, (unsigned)u << 16);
}

// ===========================================================================
// PRIMARY ws layout (bytes), total 15,846,656 — NO zero-init needed anywhere:
//   cnt     int[313][320]          @ 0           (400,640)   plain-stored by fill
//   chunkmem u32[320][313][32]     @ 400,640     (12,820,480) packed (row&31)<<14|col
//   xb      ushort[1,280,000]      @ 13,221,120  (2,560,000)  bf16 of x
//   W1p     ushort[16384]          @ 15,781,120  (32,768)     bf16 MFMA-frag order
//   W2p     ushort[16384]          @ 15,813,888  (32,768)
// ===========================================================================
#define OFF_CHUNK 400640
#define OFF_XB    13221120
#define OFF_W1P   15781120
#define OFF_W2P   15813888
#define WS_NEED   15846656

// --- build: fill (blocks 0..312) + weight-pack (313..440) + x->bf16 (441..) -
// fill: LDS hist gives per-edge rank; entry written directly at fixed
// chunk base + rank — ZERO device atomics, no pre-zeroed state; per-bin
// counts plain-stored (incl. zeros). wpack/conv overlap fill latency.
// B-frag for mfma_f32_16x16x32_bf16: lane l elem e = B[kt*32+(l>>4)*8+e][nt*16+(l&15)].
__global__ __launch_bounds__(256) void build_kernel(
        const int* __restrict__ ei, const float* __restrict__ x,
        const float* __restrict__ W1, const float* __restrict__ W2,
        int* __restrict__ cnt, unsigned* __restrict__ chunkmem,
        unsigned short* __restrict__ xb,
        unsigned short* __restrict__ W1p, unsigned short* __restrict__ W2p) {
    const int t = threadIdx.x;
    if (blockIdx.x < NCHUNK) {
        __shared__ int hist[NBIN];
        for (int b = t; b < NBIN; b += 256) hist[b] = 0;
        __syncthreads();
        const int e0 = blockIdx.x * EPB;
        #pragma unroll
        for (int i = 0; i < 8; ++i) {
            int idx = e0 + i * 256 + t;
            if (idx < NE) {
                int2 rc = *reinterpret_cast<const int2*>(ei + 2 * idx);
                int bn = rc.x >> 5;                                   // bin of 32 rows
                unsigned pk = ((unsigned)(rc.x & 31) << 14) | (unsigned)rc.y;
                int rk = atomicAdd(&hist[bn], 1);                     // LDS rank only
                if (rk < CAPC)
                    chunkmem[((size_t)bn * NCHUNK + blockIdx.x) * CAPC + rk] = pk;
            }
        }
        __syncthreads();
        for (int b = t; b < NBIN; b += 256)
            cnt[blockIdx.x * NBIN + b] = hist[b];                     // plain store
    } else if (blockIdx.x < NCHUNK + WPACK_BLOCKS) {
        int id = (blockIdx.x - NCHUNK) * 256 + t;                     // 0..32767
        const float* W = (id < 16384) ? W1 : W2;
        unsigned short* Wp = (id < 16384) ? W1p : W2p;
        int f = id & 16383;
        int e = f & 7, lane = (f >> 3) & 63, kt = (f >> 9) & 3, nt = f >> 11;
        int kglob = kt * 32 + (lane >> 4) * 8 + e;
        int jglob = nt * 16 + (lane & 15);
        Wp[f] = f2bf(W[kglob * DIM + jglob]);
    } else {
        int pid = (blockIdx.x - NCHUNK - WPACK_BLOCKS) * 256 + t;
        if (pid < CONV_THREADS) {
            int i = pid * 8;
            float4 a = *reinterpret_cast<const float4*>(x + i);
            float4 b = *reinterpret_cast<const float4*>(x + i + 4);
            u16x8 pk;
            pk[0] = f2bf(a.x); pk[1] = f2bf(a.y); pk[2] = f2bf(a.z); pk[3] = f2bf(a.w);
            pk[4] = f2bf(b.x); pk[5] = f2bf(b.y); pk[6] = f2bf(b.z); pk[7] = f2bf(b.w);
            *reinterpret_cast<u16x8*>(xb + i) = pk;
        }
    }
}

// --- fused gather + MLP (round-13 proven stages 3-4; chunk-walk prologue) ---
__global__ __launch_bounds__(256) void gather_mlp_kernel(
        const unsigned short* __restrict__ xb,
        const int* __restrict__ cnt,
        const unsigned* __restrict__ chunkmem,
        const unsigned short* __restrict__ W1p,
        const unsigned short* __restrict__ W2p,
        const float* __restrict__ b1,
        const float* __restrict__ b2,
        float* __restrict__ out) {
    __shared__ __align__(16) unsigned short aggs[16][136];
    __shared__ __align__(16) unsigned short hbuf[16][136];
    __shared__ __align__(16) unsigned short clist[16][CLCAP];
    __shared__ int lcnt[16];

    const int row0 = blockIdx.x * 16;
    const int t = threadIdx.x;

    // ---- prologue: walk this bin's 313 chunks -> dense per-node lists ----
    if (t < 16) lcnt[t] = 0;
    __syncthreads();
    {
        const int bin  = blockIdx.x >> 1;
        const int half = blockIdx.x & 1;
        for (int c = t; c < NCHUNK; c += 256) {
            int cn = cnt[c * NBIN + bin];
            cn = (cn > CAPC) ? CAPC : cn;
            const unsigned* ch = chunkmem + ((size_t)bin * NCHUNK + c) * CAPC;
            for (int k = 0; k < cn; ++k) {
                unsigned p = ch[k];
                int rl = p >> 14;                  // 0..31 within bin
                if ((rl >> 4) == half) {
                    int n = rl & 15;
                    int slot = atomicAdd(&lcnt[n], 1);
                    if (slot < CLCAP)
                        clist[n][slot] = (unsigned short)(p & 0x3FFFu);
                }
            }
        }
    }
    __syncthreads();

    // ---- dense gather: 16 lanes/node, 4-deep ILP ----
    {
        const int n = t >> 4, l = t & 15;
        int deg = lcnt[n];
        deg = (deg > CLCAP) ? CLCAP : deg;
        const size_t lo = l * 8;

        float a0[8], a1[8], a2[8], a3[8];
        {
            u16x8 v = *reinterpret_cast<const u16x8*>(xb + (size_t)(row0 + n) * DIM + lo);
            #pragma unroll
            for (int j = 0; j < 8; ++j) { a0[j] = bf2f(v[j]); a1[j] = 0.f; a2[j] = 0.f; a3[j] = 0.f; }
        }
        int k = 0;
        for (; k + 4 <= deg; k += 4) {
            int c0 = clist[n][k + 0];
            int c1 = clist[n][k + 1];
            int c2 = clist[n][k + 2];
            int c3 = clist[n][k + 3];
            u16x8 v0 = *reinterpret_cast<const u16x8*>(xb + (size_t)c0 * DIM + lo);
            u16x8 v1 = *reinterpret_cast<const u16x8*>(xb + (size_t)c1 * DIM + lo);
            u16x8 v2 = *reinterpret_cast<const u16x8*>(xb + (size_t)c2 * DIM + lo);
            u16x8 v3 = *reinterpret_cast<const u16x8*>(xb + (size_t)c3 * DIM + lo);
            #pragma unroll
            for (int j = 0; j < 8; ++j) {
                a0[j] += bf2f(v0[j]);
                a1[j] += bf2f(v1[j]);
                a2[j] += bf2f(v2[j]);
                a3[j] += bf2f(v3[j]);
            }
        }
        for (; k < deg; ++k) {
            int c = clist[n][k];
            u16x8 v = *reinterpret_cast<const u16x8*>(xb + (size_t)c * DIM + lo);
            #pragma unroll
            for (int j = 0; j < 8; ++j) a0[j] += bf2f(v[j]);
        }
        u16x8 pk;
        #pragma unroll
        for (int j = 0; j < 8; ++j) pk[j] = f2bf((a0[j] + a1[j]) + (a2[j] + a3[j]));
        *reinterpret_cast<u16x8*>(&aggs[n][l * 8]) = pk;
    }
    __syncthreads();

    // ---- MLP: wave w owns cols [32w, 32w+32) of both layers ----
    const int wid  = t >> 6;
    const int lane = t & 63;
    const int r16  = lane & 15;
    const int kg   = lane >> 4;
    const int drow = kg * 4;

    bf16x8 af[4];
    #pragma unroll
    for (int kt = 0; kt < 4; ++kt)
        af[kt] = *reinterpret_cast<const bf16x8*>(&aggs[r16][kt * 32 + kg * 8]);

    const f32x4 zero = {0.f, 0.f, 0.f, 0.f};
    f32x4 acc1[2] = {zero, zero};
    #pragma unroll
    for (int kt = 0; kt < 4; ++kt) {
        #pragma unroll
        for (int q = 0; q < 2; ++q) {
            int nt = wid * 2 + q;
            bf16x8 w = *reinterpret_cast<const bf16x8*>(
                W1p + ((nt * 4 + kt) * 64 + lane) * 8);
            acc1[q] = __builtin_amdgcn_mfma_f32_16x16x32_bf16(af[kt], w, acc1[q], 0, 0, 0);
        }
    }
    #pragma unroll
    for (int q = 0; q < 2; ++q) {
        int nt = wid * 2 + q;
        float bv = b1[nt * 16 + r16];
        #pragma unroll
        for (int r = 0; r < 4; ++r) {
            float h = fmaxf(acc1[q][r] + bv, 0.0f);
            hbuf[drow + r][nt * 16 + r16] = f2bf(h);
        }
    }
    __syncthreads();

    bf16x8 hf[4];
    #pragma unroll
    for (int kt = 0; kt < 4; ++kt)
        hf[kt] = *reinterpret_cast<const bf16x8*>(&hbuf[r16][kt * 32 + kg * 8]);

    f32x4 acc2[2] = {zero, zero};
    #pragma unroll
    for (int kt = 0; kt < 4; ++kt) {
        #pragma unroll
        for (int q = 0; q < 2; ++q) {
            int nt = wid * 2 + q;
            bf16x8 w = *reinterpret_cast<const bf16x8*>(
                W2p + ((nt * 4 + kt) * 64 + lane) * 8);
            acc2[q] = __builtin_amdgcn_mfma_f32_16x16x32_bf16(hf[kt], w, acc2[q], 0, 0, 0);
        }
    }
    #pragma unroll
    for (int q = 0; q < 2; ++q) {
        int nt = wid * 2 + q;
        float bv = b2[nt * 16 + r16];
        #pragma unroll
        for (int r = 0; r < 4; ++r)
            out[(size_t)(row0 + drow + r) * DIM + nt * 16 + r16] = acc2[q][r] + bv;
    }
}

// ===========================================================================
// FALLBACK PATH (round-2 proven f32 kernels; ws >= 2,682,880 B)
// ===========================================================================
__global__ void fb_zero_kernel(int* __restrict__ p, int n) {
    int i = blockIdx.x * blockDim.x + threadIdx.x;
    if (i < n) p[i] = 0;
}
__global__ void fb_count_kernel(const int* __restrict__ ei, int* __restrict__ deg) {
    int e = blockIdx.x * blockDim.x + threadIdx.x;
    if (e < NE) atomicAdd(&deg[ei[2 * e]], 1);
}
__global__ __launch_bounds__(1024) void fb_scan_kernel(const int* __restrict__ deg,
                                                       int* __restrict__ rowptr) {
    __shared__ int wtot[16];
    const int t = threadIdx.x;
    const int base = t * 10;
    int local[10];
    int s = 0;
    #pragma unroll
    for (int i = 0; i < 10; ++i) {
        int v = (base + i < NN) ? deg[base + i] : 0;
        local[i] = s;
        s += v;
    }
    const int mySum = s;
    #pragma unroll
    for (int off = 1; off < 64; off <<= 1) {
        int v = __shfl_up(s, (unsigned)off, 64);
        if ((t & 63) >= off) s += v;
    }
    if ((t & 63) == 63) wtot[t >> 6] = s;
    __syncthreads();
    if (t == 0) {
        int run = 0;
        #pragma unroll
        for (int i = 0; i < 16; ++i) { int v = wtot[i]; wtot[i] = run; run += v; }
    }
    __syncthreads();
    const int ex = wtot[t >> 6] + (s - mySum);
    #pragma unroll
    for (int i = 0; i < 10; ++i)
        if (base + i < NN) rowptr[base + i] = ex + local[i];
    if (t == 1023) rowptr[NN] = ex + mySum;
}
__global__ void fb_fill_kernel(const int* __restrict__ ei, const int* __restrict__ rowptr,
                               int* __restrict__ fill, int* __restrict__ colidx) {
    int e = blockIdx.x * blockDim.x + threadIdx.x;
    if (e < NE) {
        int r = ei[2 * e], c = ei[2 * e + 1];
        colidx[rowptr[r] + atomicAdd(&fill[r], 1)] = c;
    }
}
__global__ __launch_bounds__(128) void fb_gather_kernel(const float* __restrict__ x,
                                                        const int* __restrict__ rowptr,
                                                        const int* __restrict__ colidx,
                                                        float* __restrict__ agg) {
    const int n = blockIdx.x, j = threadIdx.x;
    const int s = rowptr[n], e = rowptr[n + 1];
    float acc = x[(size_t)n * DIM + j];
    float a0 = 0.f, a1 = 0.f, a2 = 0.f, a3 = 0.f;
    int k = s;
    for (; k + 4 <= e; k += 4) {
        a0 += x[(size_t)colidx[k + 0] * DIM + j];
        a1 += x[(size_t)colidx[k + 1] * DIM + j];
        a2 += x[(size_t)colidx[k + 2] * DIM + j];
        a3 += x[(size_t)colidx[k + 3] * DIM + j];
    }
    for (; k < e; ++k) acc += x[(size_t)colidx[k] * DIM + j];
    agg[(size_t)n * DIM + j] = acc + (a0 + a1) + (a2 + a3);
}
__global__ __launch_bounds__(512) void fb_mlp_kernel(
        const float* __restrict__ agg,
        const float* __restrict__ W1, const float* __restrict__ b1,
        const float* __restrict__ W2, const float* __restrict__ b2,
        float* __restrict__ out) {
    __shared__ float w1s[DIM * DIM];
    __shared__ float w2s[DIM * DIM];
    __shared__ float b1s[DIM], b2s[DIM];
    __shared__ float as[4][DIM], hs[4][DIM];
    for (int i = threadIdx.x; i < DIM * DIM; i += blockDim.x) { w1s[i] = W1[i]; w2s[i] = W2[i]; }
    if (threadIdx.x < DIM) { b1s[threadIdx.x] = b1[threadIdx.x]; b2s[threadIdx.x] = b2[threadIdx.x]; }
    __syncthreads();
    const int r = threadIdx.x >> 7, j = threadIdx.x & 127;
    for (int base = blockIdx.x * 4; base < NN; base += gridDim.x * 4) {
        int rowid = base + r;
        as[r][j] = (rowid < NN) ? agg[(size_t)rowid * DIM + j] : 0.0f;
        __syncthreads();
        float acc = b1s[j];
        #pragma unroll 8
        for (int k = 0; k < DIM; ++k) acc = fmaf(as[r][k], w1s[k * DIM + j], acc);
        hs[r][j] = fmaxf(acc, 0.0f);
        __syncthreads();
        float acc2 = b2s[j];
        #pragma unroll 8
        for (int k = 0; k < DIM; ++k) acc2 = fmaf(hs[r][k], w2s[k * DIM + j], acc2);
        if (rowid < NN) out[(size_t)rowid * DIM + j] = acc2;
        __syncthreads();
    }
}

// ===========================================================================
extern "C" void kernel_launch(void* const* d_in, const int* in_sizes, int n_in,
                              void* d_out, int out_size, void* d_ws, size_t ws_size,
                              hipStream_t stream) {
    const float* x  = (const float*)d_in[0];
    const int*   ei = (const int*)d_in[1];
    const float* W1 = (const float*)d_in[2];
    const float* b1 = (const float*)d_in[3];
    const float* W2 = (const float*)d_in[4];
    const float* b2 = (const float*)d_in[5];
    float* out = (float*)d_out;

    if (ws_size >= WS_NEED) {
        char* ws = (char*)d_ws;
        int* cnt = (int*)ws;
        unsigned* chunkmem = (unsigned*)(ws + OFF_CHUNK);
        unsigned short* xb  = (unsigned short*)(ws + OFF_XB);
        unsigned short* W1p = (unsigned short*)(ws + OFF_W1P);
        unsigned short* W2p = (unsigned short*)(ws + OFF_W2P);

        build_kernel<<<BUILD_BLOCKS, 256, 0, stream>>>(
            ei, x, W1, W2, cnt, chunkmem, xb, W1p, W2p);
        gather_mlp_kernel<<<NTILES, 256, 0, stream>>>(
            xb, cnt, chunkmem, W1p, W2p, b1, b2, out);
    } else {
        int* wsI    = (int*)d_ws;
        int* deg    = wsI;
        int* fillc  = wsI + 10240;
        int* rowptr = wsI + 20480;
        int* colidx = wsI + 30720;
        const size_t csr_bytes = (size_t)(30720 + NE) * sizeof(int);
        const size_t agg_bytes = (size_t)NN * DIM * sizeof(float);
        float* agg = (ws_size >= csr_bytes + agg_bytes)
                         ? (float*)((char*)d_ws + csr_bytes) : out;

        fb_zero_kernel<<<(20480 + 255) / 256, 256, 0, stream>>>(deg, 20480);
        fb_count_kernel<<<(NE + 255) / 256, 256, 0, stream>>>(ei, deg);
        fb_scan_kernel<<<1, 1024, 0, stream>>>(deg, rowptr);
        fb_fill_kernel<<<(NE + 255) / 256, 256, 0, stream>>>(ei, rowptr, fillc, colidx);
        fb_gather_kernel<<<NN, 128, 0, stream>>>(x, rowptr, colidx, agg);
        fb_mlp_kernel<<<256, 512, 0, stream>>>(agg, W1, b1, W2, b2, out);
    }
}

// Round 17
// 35.910 us; speedup vs baseline: 1.3990x; 1.0771x over previous
//
#include <hip/hip_runtime.h>

#define NN   10000
#define NE   640000
#define DIM  128
#define NTILES (NN / 16)        // 625
#define NBIN  320               // bins of 32 rows; valid bins 0..312
#define NCHUNK 313              // fill blocks; chunk c = fill block c
#define CAPC  32                // per-(bin,chunk) capacity; Poisson(6.4), P(>32)~1e-20
#define EPB   2048              // edges per fill block (256 thr x 8)
#define WPACK_BLOCKS 128        // 32768 weight elems / 256
#define CONV_THREADS 160000     // x->bf16: 8 floats/thread
#define CONV_BLOCKS 625
#define BUILD_BLOCKS (NCHUNK + WPACK_BLOCKS + CONV_BLOCKS)   // 1066
#define CLCAP 512               // per-node colid list capacity (round-13 proven)

typedef __attribute__((ext_vector_type(8))) short bf16x8;
typedef __attribute__((ext_vector_type(8))) unsigned short u16x8;
typedef __attribute__((ext_vector_type(4))) float f32x4;

__device__ inline unsigned short f2bf(float f) {
    unsigned u = __builtin_bit_cast(unsigned, f);
    unsigned r = (u + 0x7fffu + ((u >> 16) & 1u)) >> 16;
    return (unsigned short)r;
}
__device__ inline float bf2f(unsigned short u) {
    return __builtin_bit_cast(float, (unsigned)u << 16);
}

// ===========================================================================
// PRIMARY ws layout (bytes), total 15,846,656 — NO zero-init needed anywhere
// (round-16 proven):
//   cnt     int[313][320]          @ 0           (400,640)   plain-stored by fill
//   chunkmem u32[320][313][32]     @ 400,640     (12,820,480) packed (row&31)<<14|col
//   xb      ushort[1,280,000]      @ 13,221,120  (2,560,000)  bf16 of x
//   W1p     ushort[16384]          @ 15,781,120  (32,768)     bf16 MFMA-frag order
//   W2p     ushort[16384]          @ 15,813,888  (32,768)
// ===========================================================================
#define OFF_CHUNK 400640
#define OFF_XB    13221120
#define OFF_W1P   15781120
#define OFF_W2P   15813888
#define WS_NEED   15846656

// --- build (round-16 proven): fill + weight-pack + x->bf16 in one launch ----
__global__ __launch_bounds__(256) void build_kernel(
        const int* __restrict__ ei, const float* __restrict__ x,
        const float* __restrict__ W1, const float* __restrict__ W2,
        int* __restrict__ cnt, unsigned* __restrict__ chunkmem,
        unsigned short* __restrict__ xb,
        unsigned short* __restrict__ W1p, unsigned short* __restrict__ W2p) {
    const int t = threadIdx.x;
    if (blockIdx.x < NCHUNK) {
        __shared__ int hist[NBIN];
        for (int b = t; b < NBIN; b += 256) hist[b] = 0;
        __syncthreads();
        const int e0 = blockIdx.x * EPB;
        #pragma unroll
        for (int i = 0; i < 8; ++i) {
            int idx = e0 + i * 256 + t;
            if (idx < NE) {
                int2 rc = *reinterpret_cast<const int2*>(ei + 2 * idx);
                int bn = rc.x >> 5;                                   // bin of 32 rows
                unsigned pk = ((unsigned)(rc.x & 31) << 14) | (unsigned)rc.y;
                int rk = atomicAdd(&hist[bn], 1);                     // LDS rank only
                if (rk < CAPC)
                    chunkmem[((size_t)bn * NCHUNK + blockIdx.x) * CAPC + rk] = pk;
            }
        }
        __syncthreads();
        for (int b = t; b < NBIN; b += 256)
            cnt[blockIdx.x * NBIN + b] = hist[b];                     // plain store
    } else if (blockIdx.x < NCHUNK + WPACK_BLOCKS) {
        int id = (blockIdx.x - NCHUNK) * 256 + t;                     // 0..32767
        const float* W = (id < 16384) ? W1 : W2;
        unsigned short* Wp = (id < 16384) ? W1p : W2p;
        int f = id & 16383;
        int e = f & 7, lane = (f >> 3) & 63, kt = (f >> 9) & 3, nt = f >> 11;
        int kglob = kt * 32 + (lane >> 4) * 8 + e;
        int jglob = nt * 16 + (lane & 15);
        Wp[f] = f2bf(W[kglob * DIM + jglob]);
    } else {
        int pid = (blockIdx.x - NCHUNK - WPACK_BLOCKS) * 256 + t;
        if (pid < CONV_THREADS) {
            int i = pid * 8;
            float4 a = *reinterpret_cast<const float4*>(x + i);
            float4 b = *reinterpret_cast<const float4*>(x + i + 4);
            u16x8 pk;
            pk[0] = f2bf(a.x); pk[1] = f2bf(a.y); pk[2] = f2bf(a.z); pk[3] = f2bf(a.w);
            pk[4] = f2bf(b.x); pk[5] = f2bf(b.y); pk[6] = f2bf(b.z); pk[7] = f2bf(b.w);
            *reinterpret_cast<u16x8*>(xb + i) = pk;
        }
    }
}

// --- fused gather + MLP, 512 threads: neighbor-halved gather (2x waves) -----
// Gather: (h, n, l) = (t>>8, (t>>4)&15, t&15); h sums its half of clist[n];
// h=1 writes f32 partials to LDS; h=0 combines + stores bf16 aggs.
// MLP: 8 waves, wave w owns cols [16w, 16w+16) of both layers (4 MFMAs each).
__global__ __launch_bounds__(512) void gather_mlp_kernel(
        const unsigned short* __restrict__ xb,
        const int* __restrict__ cnt,
        const unsigned* __restrict__ chunkmem,
        const unsigned short* __restrict__ W1p,
        const unsigned short* __restrict__ W2p,
        const float* __restrict__ b1,
        const float* __restrict__ b2,
        float* __restrict__ out) {
    __shared__ __align__(16) unsigned short aggs[16][136];
    __shared__ __align__(16) unsigned short hbuf[16][136];
    __shared__ __align__(16) unsigned short clist[16][CLCAP];
    __shared__ __align__(16) float paggs[16][128];
    __shared__ int lcnt[16];

    const int row0 = blockIdx.x * 16;
    const int t = threadIdx.x;

    // ---- prologue: walk this bin's 313 chunks -> dense per-node lists ----
    if (t < 16) lcnt[t] = 0;
    __syncthreads();
    {
        const int bin  = blockIdx.x >> 1;
        const int half = blockIdx.x & 1;
        for (int c = t; c < NCHUNK; c += 512) {
            int cn = cnt[c * NBIN + bin];
            cn = (cn > CAPC) ? CAPC : cn;
            const unsigned* ch = chunkmem + ((size_t)bin * NCHUNK + c) * CAPC;
            for (int k = 0; k < cn; ++k) {
                unsigned p = ch[k];
                int rl = p >> 14;                  // 0..31 within bin
                if ((rl >> 4) == half) {
                    int n = rl & 15;
                    int slot = atomicAdd(&lcnt[n], 1);
                    if (slot < CLCAP)
                        clist[n][slot] = (unsigned short)(p & 0x3FFFu);
                }
            }
        }
    }
    __syncthreads();

    // ---- gather: each (h,n,l) sums its half of the neighbor list ----
    {
        const int h = t >> 8;              // 0 or 1
        const int n = (t >> 4) & 15;
        const int l = t & 15;
        int deg = lcnt[n];
        deg = (deg > CLCAP) ? CLCAP : deg;
        const int mid = (deg + 1) >> 1;
        const int k0 = h ? mid : 0;
        const int k1 = h ? deg : mid;
        const size_t lo = l * 8;

        float a0[8], a1[8], a2[8], a3[8];
        #pragma unroll
        for (int j = 0; j < 8; ++j) { a0[j] = 0.f; a1[j] = 0.f; a2[j] = 0.f; a3[j] = 0.f; }
        if (h == 0) {   // self row
            u16x8 v = *reinterpret_cast<const u16x8*>(xb + (size_t)(row0 + n) * DIM + lo);
            #pragma unroll
            for (int j = 0; j < 8; ++j) a0[j] = bf2f(v[j]);
        }
        int k = k0;
        for (; k + 4 <= k1; k += 4) {
            int c0 = clist[n][k + 0];
            int c1 = clist[n][k + 1];
            int c2 = clist[n][k + 2];
            int c3 = clist[n][k + 3];
            u16x8 v0 = *reinterpret_cast<const u16x8*>(xb + (size_t)c0 * DIM + lo);
            u16x8 v1 = *reinterpret_cast<const u16x8*>(xb + (size_t)c1 * DIM + lo);
            u16x8 v2 = *reinterpret_cast<const u16x8*>(xb + (size_t)c2 * DIM + lo);
            u16x8 v3 = *reinterpret_cast<const u16x8*>(xb + (size_t)c3 * DIM + lo);
            #pragma unroll
            for (int j = 0; j < 8; ++j) {
                a0[j] += bf2f(v0[j]);
                a1[j] += bf2f(v1[j]);
                a2[j] += bf2f(v2[j]);
                a3[j] += bf2f(v3[j]);
            }
        }
        for (; k < k1; ++k) {
            int c = clist[n][k];
            u16x8 v = *reinterpret_cast<const u16x8*>(xb + (size_t)c * DIM + lo);
            #pragma unroll
            for (int j = 0; j < 8; ++j) a0[j] += bf2f(v[j]);
        }
        float s[8];
        #pragma unroll
        for (int j = 0; j < 8; ++j) s[j] = (a0[j] + a1[j]) + (a2[j] + a3[j]);

        if (h == 1) {
            #pragma unroll
            for (int j = 0; j < 8; ++j) paggs[n][l * 8 + j] = s[j];
        }
        __syncthreads();
        if (h == 0) {
            u16x8 pk;
            #pragma unroll
            for (int j = 0; j < 8; ++j) pk[j] = f2bf(s[j] + paggs[n][l * 8 + j]);
            *reinterpret_cast<u16x8*>(&aggs[n][l * 8]) = pk;
        }
    }
    __syncthreads();

    // ---- MLP: 8 waves; wave w owns cols [16w, 16w+16) of both layers ----
    const int wid  = t >> 6;           // 0..7 = nt
    const int lane = t & 63;
    const int r16  = lane & 15;
    const int kg   = lane >> 4;
    const int drow = kg * 4;

    bf16x8 af[4];
    #pragma unroll
    for (int kt = 0; kt < 4; ++kt)
        af[kt] = *reinterpret_cast<const bf16x8*>(&aggs[r16][kt * 32 + kg * 8]);

    const f32x4 zero = {0.f, 0.f, 0.f, 0.f};
    f32x4 acc1 = zero;
    #pragma unroll
    for (int kt = 0; kt < 4; ++kt) {
        bf16x8 w = *reinterpret_cast<const bf16x8*>(
            W1p + ((wid * 4 + kt) * 64 + lane) * 8);
        acc1 = __builtin_amdgcn_mfma_f32_16x16x32_bf16(af[kt], w, acc1, 0, 0, 0);
    }
    {
        float bv = b1[wid * 16 + r16];
        #pragma unroll
        for (int r = 0; r < 4; ++r) {
            float h = fmaxf(acc1[r] + bv, 0.0f);
            hbuf[drow + r][wid * 16 + r16] = f2bf(h);
        }
    }
    __syncthreads();

    bf16x8 hf[4];
    #pragma unroll
    for (int kt = 0; kt < 4; ++kt)
        hf[kt] = *reinterpret_cast<const bf16x8*>(&hbuf[r16][kt * 32 + kg * 8]);

    f32x4 acc2 = zero;
    #pragma unroll
    for (int kt = 0; kt < 4; ++kt) {
        bf16x8 w = *reinterpret_cast<const bf16x8*>(
            W2p + ((wid * 4 + kt) * 64 + lane) * 8);
        acc2 = __builtin_amdgcn_mfma_f32_16x16x32_bf16(hf[kt], w, acc2, 0, 0, 0);
    }
    {
        float bv = b2[wid * 16 + r16];
        #pragma unroll
        for (int r = 0; r < 4; ++r)
            out[(size_t)(row0 + drow + r) * DIM + wid * 16 + r16] = acc2[r] + bv;
    }
}

// ===========================================================================
// FALLBACK PATH (round-2 proven f32 kernels; ws >= 2,682,880 B)
// ===========================================================================
__global__ void fb_zero_kernel(int* __restrict__ p, int n) {
    int i = blockIdx.x * blockDim.x + threadIdx.x;
    if (i < n) p[i] = 0;
}
__global__ void fb_count_kernel(const int* __restrict__ ei, int* __restrict__ deg) {
    int e = blockIdx.x * blockDim.x + threadIdx.x;
    if (e < NE) atomicAdd(&deg[ei[2 * e]], 1);
}
__global__ __launch_bounds__(1024) void fb_scan_kernel(const int* __restrict__ deg,
                                                       int* __restrict__ rowptr) {
    __shared__ int wtot[16];
    const int t = threadIdx.x;
    const int base = t * 10;
    int local[10];
    int s = 0;
    #pragma unroll
    for (int i = 0; i < 10; ++i) {
        int v = (base + i < NN) ? deg[base + i] : 0;
        local[i] = s;
        s += v;
    }
    const int mySum = s;
    #pragma unroll
    for (int off = 1; off < 64; off <<= 1) {
        int v = __shfl_up(s, (unsigned)off, 64);
        if ((t & 63) >= off) s += v;
    }
    if ((t & 63) == 63) wtot[t >> 6] = s;
    __syncthreads();
    if (t == 0) {
        int run = 0;
        #pragma unroll
        for (int i = 0; i < 16; ++i) { int v = wtot[i]; wtot[i] = run; run += v; }
    }
    __syncthreads();
    const int ex = wtot[t >> 6] + (s - mySum);
    #pragma unroll
    for (int i = 0; i < 10; ++i)
        if (base + i < NN) rowptr[base + i] = ex + local[i];
    if (t == 1023) rowptr[NN] = ex + mySum;
}
__global__ void fb_fill_kernel(const int* __restrict__ ei, const int* __restrict__ rowptr,
                               int* __restrict__ fill, int* __restrict__ colidx) {
    int e = blockIdx.x * blockDim.x + threadIdx.x;
    if (e < NE) {
        int r = ei[2 * e], c = ei[2 * e + 1];
        colidx[rowptr[r] + atomicAdd(&fill[r], 1)] = c;
    }
}
__global__ __launch_bounds__(128) void fb_gather_kernel(const float* __restrict__ x,
                                                        const int* __restrict__ rowptr,
                                                        const int* __restrict__ colidx,
                                                        float* __restrict__ agg) {
    const int n = blockIdx.x, j = threadIdx.x;
    const int s = rowptr[n], e = rowptr[n + 1];
    float acc = x[(size_t)n * DIM + j];
    float a0 = 0.f, a1 = 0.f, a2 = 0.f, a3 = 0.f;
    int k = s;
    for (; k + 4 <= e; k += 4) {
        a0 += x[(size_t)colidx[k + 0] * DIM + j];
        a1 += x[(size_t)colidx[k + 1] * DIM + j];
        a2 += x[(size_t)colidx[k + 2] * DIM + j];
        a3 += x[(size_t)colidx[k + 3] * DIM + j];
    }
    for (; k < e; ++k) acc += x[(size_t)colidx[k] * DIM + j];
    agg[(size_t)n * DIM + j] = acc + (a0 + a1) + (a2 + a3);
}
__global__ __launch_bounds__(512) void fb_mlp_kernel(
        const float* __restrict__ agg,
        const float* __restrict__ W1, const float* __restrict__ b1,
        const float* __restrict__ W2, const float* __restrict__ b2,
        float* __restrict__ out) {
    __shared__ float w1s[DIM * DIM];
    __shared__ float w2s[DIM * DIM];
    __shared__ float b1s[DIM], b2s[DIM];
    __shared__ float as[4][DIM], hs[4][DIM];
    for (int i = threadIdx.x; i < DIM * DIM; i += blockDim.x) { w1s[i] = W1[i]; w2s[i] = W2[i]; }
    if (threadIdx.x < DIM) { b1s[threadIdx.x] = b1[threadIdx.x]; b2s[threadIdx.x] = b2[threadIdx.x]; }
    __syncthreads();
    const int r = threadIdx.x >> 7, j = threadIdx.x & 127;
    for (int base = blockIdx.x * 4; base < NN; base += gridDim.x * 4) {
        int rowid = base + r;
        as[r][j] = (rowid < NN) ? agg[(size_t)rowid * DIM + j] : 0.0f;
        __syncthreads();
        float acc = b1s[j];
        #pragma unroll 8
        for (int k = 0; k < DIM; ++k) acc = fmaf(as[r][k], w1s[k * DIM + j], acc);
        hs[r][j] = fmaxf(acc, 0.0f);
        __syncthreads();
        float acc2 = b2s[j];
        #pragma unroll 8
        for (int k = 0; k < DIM; ++k) acc2 = fmaf(hs[r][k], w2s[k * DIM + j], acc2);
        if (rowid < NN) out[(size_t)rowid * DIM + j] = acc2;
        __syncthreads();
    }
}

// ===========================================================================
extern "C" void kernel_launch(void* const* d_in, const int* in_sizes, int n_in,
                              void* d_out, int out_size, void* d_ws, size_t ws_size,
                              hipStream_t stream) {
    const float* x  = (const float*)d_in[0];
    const int*   ei = (const int*)d_in[1];
    const float* W1 = (const float*)d_in[2];
    const float* b1 = (const float*)d_in[3];
    const float* W2 = (const float*)d_in[4];
    const float* b2 = (const float*)d_in[5];
    float* out = (float*)d_out;

    if (ws_size >= WS_NEED) {
        char* ws = (char*)d_ws;
        int* cnt = (int*)ws;
        unsigned* chunkmem = (unsigned*)(ws + OFF_CHUNK);
        unsigned short* xb  = (unsigned short*)(ws + OFF_XB);
        unsigned short* W1p = (unsigned short*)(ws + OFF_W1P);
        unsigned short* W2p = (unsigned short*)(ws + OFF_W2P);

        build_kernel<<<BUILD_BLOCKS, 256, 0, stream>>>(
            ei, x, W1, W2, cnt, chunkmem, xb, W1p, W2p);
        gather_mlp_kernel<<<NTILES, 512, 0, stream>>>(
            xb, cnt, chunkmem, W1p, W2p, b1, b2, out);
    } else {
        int* wsI    = (int*)d_ws;
        int* deg    = wsI;
        int* fillc  = wsI + 10240;
        int* rowptr = wsI + 20480;
        int* colidx = wsI + 30720;
        const size_t csr_bytes = (size_t)(30720 + NE) * sizeof(int);
        const size_t agg_bytes = (size_t)NN * DIM * sizeof(float);
        float* agg = (ws_size >= csr_bytes + agg_bytes)
                         ? (float*)((char*)d_ws + csr_bytes) : out;

        fb_zero_kernel<<<(20480 + 255) / 256, 256, 0, stream>>>(deg, 20480);
        fb_count_kernel<<<(NE + 255) / 256, 256, 0, stream>>>(ei, deg);
        fb_scan_kernel<<<1, 1024, 0, stream>>>(deg, rowptr);
        fb_fill_kernel<<<(NE + 255) / 256, 256, 0, stream>>>(ei, rowptr, fillc, colidx);
        fb_gather_kernel<<<NN, 128, 0, stream>>>(x, rowptr, colidx, agg);
        fb_mlp_kernel<<<256, 512, 0, stream>>>(agg, W1, b1, W2, b2, out);
    }
}